// Round 11
// baseline (299.211 us; speedup 1.0000x reference)
//
#include <hip/hip_runtime.h>
#include <hip/hip_bf16.h>
#include <cstdint>

#define N_NODES 50000
#define N_EDGES 600000
#define DCH     128
#define LN_EPS  1e-5f
#define CAP     64          // fixed adjacency capacity per node (Poisson(12): P(>64)~0)
#define CAPSH   6
#define SLICE_N (N_NODES + 1)   // rows per channel-slice, incl zero sentinel row

typedef __attribute__((ext_vector_type(8))) __bf16 bf16x8;
typedef __attribute__((ext_vector_type(4))) float  f32x4;
typedef __attribute__((ext_vector_type(4))) int          int4e;
typedef __attribute__((ext_vector_type(2))) unsigned int uint2e;

__device__ inline unsigned short f2bf(float f) {
    unsigned int b; __builtin_memcpy(&b, &f, 4);
    b = b + 0x7fffu + ((b >> 16) & 1u);   // round-to-nearest-even
    return (unsigned short)(b >> 16);
}
__device__ inline float bf_lo(unsigned int u) {
    unsigned int t = u << 16; float f; __builtin_memcpy(&f, &t, 4); return f;
}
__device__ inline float bf_hi(unsigned int u) {
    unsigned int t = u & 0xffff0000u; float f; __builtin_memcpy(&f, &t, 4); return f;
}

// ---------------- fill: inline dtype detect + atomic slot placement ----------
// cntp is PADDED: one counter per 64 B line (d<<4) -> ~12 atomics/line instead
// of ~192, removing the cross-XCD line ping-pong chain (r10: fill 43 us).
__global__ __launch_bounds__(256) void fill_k(const int* __restrict__ ei,
                                              int* __restrict__ cntp, int* __restrict__ csr) {
    __shared__ int sbad;
    int tid = threadIdx.x;
    if (tid == 0) sbad = 0;
    __syncthreads();
    // int64-vs-int32 probe: same 512 samples every block (L2-hot). If buffer is
    // int32, an int64 read has a random node id in its high word -> out of range.
    const long long* e64 = (const long long*)ei;
    long long v = e64[tid];
    long long w = e64[300000 + tid];
    if (v < 0 || v >= N_NODES || w < 0 || w >= N_NODES) sbad = 1;
    __syncthreads();
    int is64 = (sbad == 0);

    int e = blockIdx.x * 256 + tid;
    if (e >= N_EDGES) return;
    long long sv = is64 ? e64[e]           : (long long)ei[e];
    long long dv = is64 ? e64[N_EDGES + e] : (long long)ei[N_EDGES + e];
    int s = (int)(sv < 0 ? 0 : (sv >= N_NODES ? N_NODES - 1 : sv));
    int d = (int)(dv < 0 ? 0 : (dv >= N_NODES ? N_NODES - 1 : dv));
    int pos = atomicAdd(&cntp[d << 4], 1);
    if (pos < CAP) csr[(d << CAPSH) + pos] = s;   // slots >= cnt stay poison; agg clamps
}

// ---------------- prep: cvt x->xbf (sliced, *rsqrt(deg)) + dense cnt + W^T + sentinels
#define CVT_T    ((N_NODES + 1) * 32)                 // 1600032
#define CNTD_OFF CVT_T
#define TRAN_OFF (CNTD_OFF + N_NODES)                 // 1650032
#define SENT_OFF (TRAN_OFF + 3 * 128 * 128)           // 1699184
#define PREP_T   (SENT_OFF + 128)                     // 1699312

__global__ __launch_bounds__(256) void prep_k(
        const float* __restrict__ x, const int* __restrict__ cntp,
        const float* __restrict__ W1, const float* __restrict__ W2,
        const float* __restrict__ W3,
        unsigned short* __restrict__ xbf, int* __restrict__ cnt,
        unsigned short* __restrict__ Wt, unsigned short* __restrict__ hbuf) {
    int id = blockIdx.x * 256 + threadIdx.x;
    if (id < CVT_T) {                                  // x -> xbf (slice-major, scaled)
        int node = id >> 5;
        int co = (id & 31) * 4;
        int slice = co >> 5, off = co & 31;
        uint2 r; r.x = 0u; r.y = 0u;
        if (node < N_NODES) {
            float4 v = *(const float4*)(x + (size_t)node * DCH + co);
            float d = rsqrtf((float)cntp[node << 4] + 3.0f);
            r.x = ((unsigned int)f2bf(v.y * d) << 16) | (unsigned int)f2bf(v.x * d);
            r.y = ((unsigned int)f2bf(v.w * d) << 16) | (unsigned int)f2bf(v.z * d);
        }
        *(uint2*)(xbf + ((size_t)slice * SLICE_N + node) * 32 + off) = r;
    } else if (id < TRAN_OFF) {                        // compact padded cnt -> dense
        int i = id - CNTD_OFF;
        cnt[i] = cntp[i << 4];
    } else if (id < SENT_OFF) {                        // W -> Wt (bf16 [mat][n][k])
        int t = id - TRAN_OFF;
        int mat = t >> 14;
        int o = t & 16383;
        int n = o >> 7, k = o & 127;
        const float* W = (mat == 0) ? W1 : ((mat == 1) ? W2 : W3);
        Wt[t] = f2bf(W[k * 128 + n]);
    } else if (id < PREP_T) {                          // zero hbuf sentinel rows
        int i = id - SENT_OFF;
        hbuf[((size_t)(i >> 5) * SLICE_N + N_NODES) * 32 + (i & 31)] = 0;
    }
}

// ------- Sliced aggregation v4: wave = 8 nodes x 1 slice, 8 edges/iteration.
// 64 lanes = 8 groups of 8; lane owns 4 channels (uint2 = 8 B of the 64 B row)
// -> per-lane accumulation, NO cross-lane reduction. 8 gathers in flight/lane.
// deg = cnt + f (f = 1+fill), di = rsqrtf(cnt+f) computed inline.
// Slots >= cnt clamp to zero-sentinel row N (hot L1 line, ~free).
// blockIdx = grp*4 + slice pins each slice in L2 (r7/r8: FETCH ~24 MB compulsory).

__global__ __launch_bounds__(128) void agg_k(
        const unsigned short* __restrict__ hs, unsigned short* __restrict__ outb,
        const int* __restrict__ cnt, const int* __restrict__ csr, float f) {
    int slice = blockIdx.x & 3;
    int grp   = blockIdx.x >> 2;                 // 0..3124
    int wv    = threadIdx.x >> 6;                // 0..1
    int lane  = threadIdx.x & 63;
    int g     = lane >> 3;                       // node group 0..7
    int l8    = lane & 7;                        // 8 B chunk within 64 B row
    int node  = grp * 16 + wv * 8 + g;           // 3125*16 = 50000 exact

    const uint2* hp = (const uint2*)(hs + (size_t)slice * SLICE_N * 32);  // row = 8 uint2
    int cn = cnt[node];
    float di = rsqrtf((float)cn + f);
    int pc = (cn + 7) & ~7; if (pc > CAP) pc = CAP;
    pc = max(pc, __shfl_xor(pc, 8));
    pc = max(pc, __shfl_xor(pc, 16));
    pc = max(pc, __shfl_xor(pc, 32));            // wave-uniform loop bound

    const int4e* pcsr = (const int4e*)(csr + ((size_t)node << CAPSH));
    float a[8][4];
    #pragma unroll
    for (int j = 0; j < 8; j++)
        #pragma unroll
        for (int ch = 0; ch < 4; ch++) a[j][ch] = 0.f;

    for (int i = 0; i < pc; i += 8) {
        int4e ea = __builtin_nontemporal_load(&pcsr[(i >> 2) + 0]);
        int4e eb = __builtin_nontemporal_load(&pcsr[(i >> 2) + 1]);
        int e[8];
        e[0] = (i + 0 < cn) ? ea.x : N_NODES;
        e[1] = (i + 1 < cn) ? ea.y : N_NODES;
        e[2] = (i + 2 < cn) ? ea.z : N_NODES;
        e[3] = (i + 3 < cn) ? ea.w : N_NODES;
        e[4] = (i + 4 < cn) ? eb.x : N_NODES;
        e[5] = (i + 5 < cn) ? eb.y : N_NODES;
        e[6] = (i + 6 < cn) ? eb.z : N_NODES;
        e[7] = (i + 7 < cn) ? eb.w : N_NODES;
        uint2 u[8];
        #pragma unroll
        for (int j = 0; j < 8; j++) u[j] = hp[(size_t)e[j] * 8 + l8];
        #pragma unroll
        for (int j = 0; j < 8; j++) {
            a[j][0] += bf_lo(u[j].x); a[j][1] += bf_hi(u[j].x);
            a[j][2] += bf_lo(u[j].y); a[j][3] += bf_hi(u[j].y);
        }
    }
    float c0 = ((a[0][0]+a[1][0])+(a[2][0]+a[3][0])) + ((a[4][0]+a[5][0])+(a[6][0]+a[7][0]));
    float c1 = ((a[0][1]+a[1][1])+(a[2][1]+a[3][1])) + ((a[4][1]+a[5][1])+(a[6][1]+a[7][1]));
    float c2 = ((a[0][2]+a[1][2])+(a[2][2]+a[3][2])) + ((a[4][2]+a[5][2])+(a[6][2]+a[7][2]));
    float c3 = ((a[0][3]+a[1][3])+(a[2][3]+a[3][3])) + ((a[4][3]+a[5][3])+(a[6][3]+a[7][3]));
    uint2 us = hp[(size_t)node * 8 + l8];
    c0 = di * (c0 + f * bf_lo(us.x));
    c1 = di * (c1 + f * bf_hi(us.x));
    c2 = di * (c2 + f * bf_lo(us.y));
    c3 = di * (c3 + f * bf_hi(us.y));
    uint2e res;
    res.x = ((unsigned int)f2bf(c1) << 16) | (unsigned int)f2bf(c0);
    res.y = ((unsigned int)f2bf(c3) << 16) | (unsigned int)f2bf(c2);
    __builtin_nontemporal_store(res,
        (uint2e*)(outb + (size_t)slice * SLICE_N * 32) + (size_t)node * 8 + l8);
}

// ---------------- MFMA GEMM (16x16x32 bf16), 32 rows/wave, slice-major A ----
// A frag kt = slice kt, offset q*8 (contiguous 16 B). C/D: col=lane&15,
// row=quad*4+reg.
// MODE 0: out_bf (slice-major) = rsqrt(cnt[row]+cadd)*relu(LN(A@W+bias)*g+b)
// MODE 1: out_f  (node-major)  = A@W + bias + resid

template<int MODE>
__global__ __launch_bounds__(256) void gemm_k(
        const unsigned short* __restrict__ A,      // bf16 slice-major [4][SLICE_N][32]
        const unsigned short* __restrict__ Wt,     // bf16 [n][k] 128x128
        const float* __restrict__ bias,
        const float* __restrict__ gamma,
        const float* __restrict__ beta,
        const int* __restrict__ cnt, float cadd,   // MODE 0 epilogue scale
        const float* __restrict__ resid,           // MODE 1
        unsigned short* __restrict__ out_bf,       // MODE 0, slice-major
        float* __restrict__ out_f) {               // MODE 1, node-major
    int lane = threadIdx.x & 63;
    int wv   = threadIdx.x >> 6;
    int r0   = (blockIdx.x * 4 + wv) * 32;         // 32 rows per wave
    int m = lane & 15, q = lane >> 4;

    bf16x8 afr[2][4];
    #pragma unroll
    for (int mt = 0; mt < 2; mt++) {
        int arow = r0 + mt * 16 + m; if (arow >= N_NODES) arow = N_NODES - 1;
        #pragma unroll
        for (int kt = 0; kt < 4; kt++)
            afr[mt][kt] = __builtin_nontemporal_load(
                (const bf16x8*)(A + ((size_t)kt * SLICE_N + arow) * 32 + q * 8));
    }

    f32x4 acc[2][8];
    #pragma unroll
    for (int nt = 0; nt < 8; nt++) {
        f32x4 c0 = {0.f,0.f,0.f,0.f}, c1 = {0.f,0.f,0.f,0.f};
        const unsigned short* bp = Wt + (size_t)(nt * 16 + m) * DCH + q * 8;
        #pragma unroll
        for (int kt = 0; kt < 4; kt++) {
            bf16x8 bfr = *(const bf16x8*)(bp + kt * 32);
            c0 = __builtin_amdgcn_mfma_f32_16x16x32_bf16(afr[0][kt], bfr, c0, 0, 0, 0);
            c1 = __builtin_amdgcn_mfma_f32_16x16x32_bf16(afr[1][kt], bfr, c1, 0, 0, 0);
        }
        acc[0][nt] = c0; acc[1][nt] = c1;
    }

    float bv[8];
    #pragma unroll
    for (int nt = 0; nt < 8; nt++) bv[nt] = bias[nt * 16 + m];

    if (MODE == 0) {
        float gv[8], bev[8];
        #pragma unroll
        for (int nt = 0; nt < 8; nt++) { gv[nt] = gamma[nt*16+m]; bev[nt] = beta[nt*16+m]; }
        #pragma unroll
        for (int mt = 0; mt < 2; mt++) {
            #pragma unroll
            for (int nt = 0; nt < 8; nt++)
                #pragma unroll
                for (int r = 0; r < 4; r++) acc[mt][nt][r] += bv[nt];
            #pragma unroll
            for (int r = 0; r < 4; r++) {
                float s = 0.f, qs = 0.f;
                #pragma unroll
                for (int nt = 0; nt < 8; nt++) { float v = acc[mt][nt][r]; s += v; qs += v*v; }
                #pragma unroll
                for (int msk = 1; msk < 16; msk <<= 1) {
                    s  += __shfl_xor(s,  msk, 16);
                    qs += __shfl_xor(qs, msk, 16);
                }
                float mean = s * (1.f / 128.f);
                float var  = fmaxf(qs * (1.f / 128.f) - mean * mean, 0.f);
                float rstd = rsqrtf(var + LN_EPS);
                int row = r0 + mt * 16 + q * 4 + r;
                if (row < N_NODES) {
                    float dscale = rsqrtf((float)cnt[row] + cadd);
                    #pragma unroll
                    for (int nt = 0; nt < 8; nt++) {
                        float v = (acc[mt][nt][r] - mean) * rstd * gv[nt] + bev[nt];
                        v = fmaxf(v, 0.f) * dscale;
                        __builtin_nontemporal_store(f2bf(v),
                            out_bf + ((size_t)(nt >> 1) * SLICE_N + row) * 32
                                   + (nt & 1) * 16 + m);
                    }
                }
            }
        }
    } else {
        #pragma unroll
        for (int mt = 0; mt < 2; mt++)
            #pragma unroll
            for (int r = 0; r < 4; r++) {
                int row = r0 + mt * 16 + q * 4 + r;
                if (row < N_NODES) {
                    #pragma unroll
                    for (int nt = 0; nt < 8; nt++) {
                        float v = acc[mt][nt][r] + bv[nt]
                                + resid[(size_t)row * DCH + nt * 16 + m];
                        out_f[(size_t)row * DCH + nt * 16 + m] = v;
                    }
                }
            }
    }
}

// ---------------- launcher (8 dispatches + 1 memset) ----------------

extern "C" void kernel_launch(void* const* d_in, const int* in_sizes, int n_in,
                              void* d_out, int out_size, void* d_ws, size_t ws_size,
                              hipStream_t stream) {
    const float* x   = (const float*)d_in[0];
    const int*   ei  = (const int*)d_in[1];
    const float* W1  = (const float*)d_in[2];
    const float* b1  = (const float*)d_in[3];
    const float* g1  = (const float*)d_in[4];
    const float* be1 = (const float*)d_in[5];
    const float* W2  = (const float*)d_in[6];
    const float* b2  = (const float*)d_in[7];
    const float* g2  = (const float*)d_in[8];
    const float* be2 = (const float*)d_in[9];
    const float* W3  = (const float*)d_in[10];
    const float* b3  = (const float*)d_in[11];
    float* out = (float*)d_out;

    char* p = (char*)d_ws;
    auto alloc = [&](size_t bytes) -> void* {
        void* r = (void*)p; p += (bytes + 255) & ~(size_t)255; return r;
    };
    int*   cntp  = (int*)  alloc((size_t)N_NODES * 16 * 4);       // padded: 1/line, 3.2 MB
    int*   cnt   = (int*)  alloc((size_t)N_NODES * 4);            // dense
    int*   csr   = (int*)  alloc((size_t)N_NODES * CAP * 4);      // 12.8 MB
    unsigned short* Wt   = (unsigned short*)alloc((size_t)3 * 128 * 128 * 2);
    unsigned short* aggb = (unsigned short*)alloc((size_t)4 * SLICE_N * 32 * 2);
    unsigned short* xbf  = (unsigned short*)alloc((size_t)4 * SLICE_N * 32 * 2);
    unsigned short* hbuf = (unsigned short*)alloc((size_t)4 * SLICE_N * 32 * 2);

    (void)hipMemsetAsync(cntp, 0, (size_t)N_NODES * 16 * 4, stream);
    fill_k<<<(N_EDGES + 255) / 256, 256, 0, stream>>>(ei, cntp, csr);     // 2344
    prep_k<<<(PREP_T + 255) / 256, 256, 0, stream>>>(x, cntp, W1, W2, W3,
                                                     xbf, cnt, Wt, hbuf); // 6638

    const int A_BLOCKS = 3125 * 4;                // grp*4 + slice, 128-thread blocks
    const int G_BLOCKS = (N_NODES + 127) / 128;   // 391

    // layer 1: agg(f=3) -> @W1+b1 -> LN,relu, *rsqrt(cnt+3) -> hbuf
    agg_k<<<A_BLOCKS, 128, 0, stream>>>(xbf, aggb, cnt, csr, 3.0f);
    gemm_k<0><<<G_BLOCKS, 256, 0, stream>>>(aggb, Wt, b1, g1, be1, cnt, 3.0f, nullptr, hbuf, nullptr);
    // layer 2: agg(f=3) -> @W2+b2 -> LN,relu, *rsqrt(cnt+2) -> hbuf
    agg_k<<<A_BLOCKS, 128, 0, stream>>>(hbuf, aggb, cnt, csr, 3.0f);
    gemm_k<0><<<G_BLOCKS, 256, 0, stream>>>(aggb, Wt + 16384, b2, g2, be2, cnt, 2.0f, nullptr, hbuf, nullptr);
    // layer 3: agg(f=2) -> @W3+b3 + x -> f32 d_out
    agg_k<<<A_BLOCKS, 128, 0, stream>>>(hbuf, aggb, cnt, csr, 2.0f);
    gemm_k<1><<<G_BLOCKS, 256, 0, stream>>>(aggb, Wt + 32768, b3, nullptr, nullptr, nullptr, 0.0f, x, nullptr, out);
}